// Round 5
// baseline (437.642 us; speedup 1.0000x reference)
//
#include <hip/hip_runtime.h>
#include <hip/hip_bf16.h>

#define B 4
#define H 480
#define W 640
#define HW (H*W)
#define BHW (B*H*W)
#define NKP 1024
#define THRESH 0.005f
#define CAP 16384
#define NCOL (B*NKP)
#define KTOT 704

typedef __attribute__((ext_vector_type(4))) short s4v;
typedef __attribute__((ext_vector_type(8))) short s8v;
typedef __attribute__((ext_vector_type(4))) float f4v;

__device__ __forceinline__ short f2bf(float f) {
    __hip_bfloat16 h = __float2bfloat16(f);
    return *(short*)&h;
}
__device__ __forceinline__ float bf2f(unsigned short u) {
    return __uint_as_float(((unsigned)u) << 16);
}

// ================= fused weights + bias + counter zero =================
__global__ void fuse_all(const float* __restrict__ merge_w, const float* __restrict__ merge_b,
                         const float* __restrict__ lin0_w, const float* __restrict__ lin0_b,
                         const float* __restrict__ lin1_w, const float* __restrict__ lin1_b,
                         const float* __restrict__ lin2_w, const float* __restrict__ lin2_b,
                         float* __restrict__ Mw, float* __restrict__ biasf, int* __restrict__ cnt) {
    if (blockIdx.x == 704) {
        int o = threadIdx.x;
        if (o < 4) cnt[o * 64] = 0;
        float acc = merge_b[o];
        for (int k = 0; k < 64; ++k)  acc += merge_w[o * KTOT + k] * lin2_b[k];
        for (int k = 0; k < 128; ++k) acc += merge_w[o * KTOT + 64 + k] * lin1_b[k];
        for (int k = 0; k < 256; ++k) acc += merge_w[o * KTOT + 448 + k] * lin0_b[k];
        biasf[o] = acc;
        return;
    }
    int e = blockIdx.x * 256 + threadIdx.x;
    int o = e / KTOT;
    int j = e - o * KTOT;
    float acc = 0.0f;
    if (j < 64) {
        for (int k = 0; k < 64; ++k) acc += merge_w[o * KTOT + k] * lin2_w[k * 64 + j];
    } else if (j < 192) {
        int jj = j - 64;
        for (int k = 0; k < 128; ++k) acc += merge_w[o * KTOT + 64 + k] * lin1_w[k * 128 + jj];
    } else if (j < 448) {
        acc = merge_w[o * KTOT + j];
    } else {
        int jj = j - 448;
        for (int k = 0; k < 256; ++k) acc += merge_w[o * KTOT + 448 + k] * lin0_w[k * 256 + jj];
    }
    Mw[o * KTOT + j] = acc;
}

// ================= NMS stage 1: mask0 = (S == pool9(S)) =================
__global__ __launch_bounds__(256) void nms1(const float* __restrict__ scores,
                                            float* __restrict__ mask) {
    __shared__ float tile[40][40];
    __shared__ float hm[40][32];
    int bz = blockIdx.z;
    int x0 = blockIdx.x * 32, y0 = blockIdx.y * 32;
    const float* sp = scores + bz * HW;
    for (int t = threadIdx.x; t < 1600; t += 256) {
        int ly = t / 40, lx = t - ly * 40;
        int gy = y0 - 4 + ly, gx = x0 - 4 + lx;
        tile[ly][lx] = (gy >= 0 && gy < H && gx >= 0 && gx < W) ? sp[gy * W + gx] : -INFINITY;
    }
    __syncthreads();
    for (int t = threadIdx.x; t < 1280; t += 256) {
        int ly = t >> 5, lx = t & 31;
        float m = tile[ly][lx];
        #pragma unroll
        for (int d = 1; d < 9; ++d) m = fmaxf(m, tile[ly][lx + d]);
        hm[ly][lx] = m;
    }
    __syncthreads();
    for (int t = threadIdx.x; t < 1024; t += 256) {
        int ly = t >> 5, lx = t & 31;
        float m = hm[ly][lx];
        #pragma unroll
        for (int d = 1; d < 9; ++d) m = fmaxf(m, hm[ly + d][lx]);
        float s = tile[ly + 4][lx + 4];
        mask[bz * HW + (y0 + ly) * W + x0 + lx] = (s == m) ? 1.0f : 0.0f;
    }
}

// ===== NMS stage 2: remaining 4 pools fused in LDS + compaction =====
__global__ __launch_bounds__(256) void nms2_compact(const float* __restrict__ scores,
                                                    const float* __restrict__ mask0,
                                                    unsigned long long* __restrict__ cand,
                                                    int* __restrict__ cnt) {
    __shared__ float Sm[56 * 56];
    __shared__ float Mm[64 * 64];
    __shared__ float Zm[56 * 56];
    __shared__ float Tm[64 * 56];
    __shared__ int lcnt, gbase;
    int bz = blockIdx.z;
    int x0 = blockIdx.x * 32, y0 = blockIdx.y * 32;
    const float* sp = scores + bz * HW;
    const float* mp = mask0 + bz * HW;
    if (threadIdx.x == 0) lcnt = 0;
    for (int t = threadIdx.x; t < 4096; t += 256) {
        int ly = t >> 6, lx = t & 63;
        int gy = y0 - 16 + ly, gx = x0 - 16 + lx;
        Mm[t] = (gy >= 0 && gy < H && gx >= 0 && gx < W) ? mp[gy * W + gx] : 0.0f;
    }
    for (int t = threadIdx.x; t < 3136; t += 256) {
        int i = t / 56, j = t - i * 56;
        int gy = y0 - 12 + i, gx = x0 - 12 + j;
        Sm[t] = (gy >= 0 && gy < H && gx >= 0 && gx < W) ? sp[gy * W + gx] : -1.0f;
    }
    __syncthreads();
    for (int t = threadIdx.x; t < 3584; t += 256) {
        int i = t / 56, c = t - i * 56;
        float m = Mm[i * 64 + c];
        #pragma unroll
        for (int d = 1; d < 9; ++d) m = fmaxf(m, Mm[i * 64 + c + d]);
        Tm[i * 56 + c] = m;
    }
    __syncthreads();
    for (int t = threadIdx.x; t < 3136; t += 256) {
        int i = t / 56, c = t - i * 56;
        float m = Tm[i * 56 + c];
        #pragma unroll
        for (int d = 1; d < 9; ++d) m = fmaxf(m, Tm[(i + d) * 56 + c]);
        Zm[t] = (m > 0.0f) ? -1.0f : Sm[t];
    }
    __syncthreads();
    for (int t = threadIdx.x; t < 2688; t += 256) {
        int i = t / 48, c = t - i * 48;
        float m = Zm[i * 56 + c];
        #pragma unroll
        for (int d = 1; d < 9; ++d) m = fmaxf(m, Zm[i * 56 + c + d]);
        Tm[i * 56 + c] = m;
    }
    __syncthreads();
    for (int t = threadIdx.x; t < 2304; t += 256) {
        int r = t / 48, c = t - r * 48;
        float m = Tm[r * 56 + c];
        #pragma unroll
        for (int d = 1; d < 9; ++d) m = fmaxf(m, Tm[(r + d) * 56 + c]);
        float Zc = Zm[(r + 4) * 56 + c + 4];
        int mi = (r + 8) * 64 + c + 8;
        bool nm = (Zc == m) && (Zc >= 0.0f);
        Mm[mi] = (Mm[mi] != 0.0f || nm) ? 1.0f : 0.0f;
    }
    __syncthreads();
    for (int t = threadIdx.x; t < 1920; t += 256) {
        int r = t / 40, c = t - r * 40;
        float m = Mm[(r + 8) * 64 + c + 8];
        #pragma unroll
        for (int d = 1; d < 9; ++d) m = fmaxf(m, Mm[(r + 8) * 64 + c + 8 + d]);
        Tm[r * 56 + c] = m;
    }
    __syncthreads();
    for (int t = threadIdx.x; t < 1600; t += 256) {
        int r = t / 40, c = t - r * 40;
        float m = Tm[r * 56 + c];
        #pragma unroll
        for (int d = 1; d < 9; ++d) m = fmaxf(m, Tm[(r + d) * 56 + c]);
        int zi = (r + 8) * 56 + c + 8;
        Zm[zi] = (m > 0.0f) ? -1.0f : Sm[zi];
    }
    __syncthreads();
    for (int t = threadIdx.x; t < 1280; t += 256) {
        int r = t / 32, c = t & 31;
        float m = Zm[(r + 8) * 56 + c + 8];
        #pragma unroll
        for (int d = 1; d < 9; ++d) m = fmaxf(m, Zm[(r + 8) * 56 + c + 8 + d]);
        Tm[r * 56 + c] = m;
    }
    __syncthreads();
    unsigned long long keys[4];
    int nl = 0;
    #pragma unroll
    for (int q = 0; q < 4; ++q) {
        int t = threadIdx.x + q * 256;
        int r3 = t >> 5, c = t & 31;
        float m = Tm[r3 * 56 + c];
        #pragma unroll
        for (int d = 1; d < 9; ++d) m = fmaxf(m, Tm[(r3 + d) * 56 + c]);
        float Zc = Zm[(r3 + 12) * 56 + c + 12];
        bool fin = (Mm[(r3 + 16) * 64 + c + 16] != 0.0f) || ((Zc == m) && (Zc >= 0.0f));
        int gy = y0 + r3, gx = x0 + c;
        float sc = Sm[(r3 + 12) * 56 + c + 12];
        if (fin && gy >= 4 && gy < H - 4 && gx >= 4 && gx < W - 4 && sc > THRESH) {
            unsigned r = (unsigned)(gy * W + gx);
            unsigned bits = __float_as_uint(sc) | 0x80000000u;
            keys[nl++] = ((unsigned long long)bits << 32) |
                         (unsigned long long)(0xFFFFFFFFu - r);
        }
    }
    int lpos = 0;
    if (nl) lpos = atomicAdd(&lcnt, nl);
    __syncthreads();
    if (threadIdx.x == 0) gbase = (lcnt > 0) ? atomicAdd(&cnt[bz * 64], lcnt) : 0;
    __syncthreads();
    for (int j = 0; j < nl; ++j) {
        int p = gbase + lpos + j;
        if (p < CAP) cand[(size_t)bz * CAP + p] = keys[j];
    }
}

// ===== topk: two-level histogram select + bitonic (wave-aggregated atomics, no perm) =====
__global__ __launch_bounds__(1024) void topk(const unsigned long long* __restrict__ cand,
                                             const int* __restrict__ cnt,
                                             float* __restrict__ out, int* __restrict__ fidx) {
    __shared__ int hist[2048];
    __shared__ unsigned long long buf[4096];
    __shared__ int scnt, spiv1, spiv2, sabove;
    int b = blockIdx.x, tid = threadIdx.x;
    int m = cnt[b * 64]; if (m > CAP) m = CAP;
    const unsigned long long* cb = cand + (size_t)b * CAP;
    int target = (m < 1024) ? m : 1024;

    hist[tid] = 0; hist[tid + 1024] = 0;
    if (tid == 0) { scnt = 0; spiv1 = 2048; spiv2 = 0; sabove = 0; }
    __syncthreads();
    // pass 1: histogram bits [63:53], wave-aggregated (97% of keys share a bin)
    for (int i = tid; i < m; i += 1024) {
        int bin = (int)(cb[i] >> 53) & 0x7FF;
        int first = __builtin_amdgcn_readfirstlane(bin);
        unsigned long long same = __ballot(bin == first);
        if (same == ~0ULL) {
            if ((tid & 63) == 0) atomicAdd(&hist[first], 64);
        } else {
            atomicAdd(&hist[bin], 1);
        }
    }
    __syncthreads();
    for (int d = 1; d < 2048; d <<= 1) {
        int v0 = hist[tid] + ((tid + d < 2048) ? hist[tid + d] : 0);
        int v1 = hist[tid + 1024] + ((tid + 1024 + d < 2048) ? hist[tid + 1024 + d] : 0);
        __syncthreads();
        hist[tid] = v0; hist[tid + 1024] = v1;
        __syncthreads();
    }
    if (target > 0) {
        for (int t = tid; t < 2048; t += 1024) {
            int c = hist[t];
            int cn = (t < 2047) ? hist[t + 1] : 0;
            if (c >= target && cn < target) { spiv1 = t; sabove = cn; }
        }
    }
    __syncthreads();
    int piv1 = spiv1;
    int target2 = target - sabove;
    hist[tid] = 0; hist[tid + 1024] = 0;
    __syncthreads();
    for (int i = tid; i < m; i += 1024) {
        unsigned long long k = cb[i];
        if (((int)(k >> 53) & 0x7FF) == piv1)
            atomicAdd(&hist[(int)(k >> 42) & 0x7FF], 1);
    }
    __syncthreads();
    for (int d = 1; d < 2048; d <<= 1) {
        int v0 = hist[tid] + ((tid + d < 2048) ? hist[tid + d] : 0);
        int v1 = hist[tid + 1024] + ((tid + 1024 + d < 2048) ? hist[tid + 1024 + d] : 0);
        __syncthreads();
        hist[tid] = v0; hist[tid + 1024] = v1;
        __syncthreads();
    }
    if (target > 0) {
        for (int t = tid; t < 2048; t += 1024) {
            int c = hist[t];
            int cn = (t < 2047) ? hist[t + 1] : 0;
            if (c >= target2 && cn < target2) spiv2 = t;
        }
    }
    __syncthreads();
    int piv2 = spiv2;
    for (int i = tid; i < m; i += 1024) {
        unsigned long long k = cb[i];
        int b1 = (int)(k >> 53) & 0x7FF;
        bool sel = (target > 0) &&
                   (b1 > piv1 || (b1 == piv1 && (((int)(k >> 42) & 0x7FF) >= piv2)));
        if (sel) {
            int p = atomicAdd(&scnt, 1);
            if (p < 4096) buf[p] = k;
        }
    }
    __syncthreads();
    int sc_ = scnt; if (sc_ > 4096) sc_ = 4096;
    int ns = 1024; while (ns < sc_) ns <<= 1;
    for (int t = tid; t < ns; t += 1024) if (t >= sc_) buf[t] = 0ULL;
    __syncthreads();
    for (int k = 2; k <= ns; k <<= 1)
        for (int j = k >> 1; j > 0; j >>= 1) {
            __syncthreads();
            for (int t = tid; t < ns; t += 1024) {
                int ixj = t ^ j;
                if (ixj > t) {
                    unsigned long long a = buf[t], bb = buf[ixj];
                    if (((t & k) == 0) ? (a < bb) : (a > bb)) { buf[t] = bb; buf[ixj] = a; }
                }
            }
        }
    __syncthreads();
    unsigned long long key = buf[tid];
    float kx, ky, sc;
    unsigned idx;
    if (key != 0ULL) {
        unsigned ord = (unsigned)(key >> 32);
        sc = __uint_as_float(ord ^ 0x80000000u);
        idx = 0xFFFFFFFFu - (unsigned)(key & 0xFFFFFFFFu);
        kx = (float)(idx % W);
        ky = (float)(idx / W);
    } else {
        sc = -1.0f; idx = 0; kx = 0.0f; ky = 0.0f;
    }
    int bn = b * NKP + tid;
    out[bn * 2 + 0] = kx;
    out[bn * 2 + 1] = ky;
    out[B * NKP * 2 + bn] = sc;
    fidx[bn] = (int)idx;
}

// ===== CHW fp32 -> HWC bf16 transpose =====
template <int CMAP>
__global__ __launch_bounds__(256) void transpose_hwc(const float* __restrict__ in,
                                                     unsigned short* __restrict__ out,
                                                     int h, int w) {
    __shared__ float Ts[64][65];
    int lx = threadIdx.x & 63, lr = threadIdx.x >> 6;
    int x0 = blockIdx.x * 64;
    int y = blockIdx.y;
    int bz = blockIdx.z;                       // b*(CMAP/64) + ctile
    int b = bz / (CMAP / 64);
    int c0 = (bz % (CMAP / 64)) * 64;
    int x = x0 + lx;
    #pragma unroll
    for (int i = 0; i < 16; ++i) {
        int cl = lr + i * 4;
        float v = 0.0f;
        if (x < w) v = in[(((size_t)(b * CMAP + c0 + cl)) * h + y) * w + x];
        Ts[cl][lx] = v;
    }
    __syncthreads();
    #pragma unroll
    for (int j = 0; j < 16; ++j) {
        int xl = lr + j * 4;
        int xg = x0 + xl;
        if (xg < w)
            out[((size_t)(b * h + y) * w + xg) * CMAP + c0 + lx] =
                (unsigned short)f2bf(Ts[lx][xl]);
    }
}

// ===== coalesced descriptor gather from HWC bf16 maps =====
__global__ __launch_bounds__(704) void sample_hwc(const unsigned short* __restrict__ T1,
                                                  const unsigned short* __restrict__ T2,
                                                  const unsigned short* __restrict__ T3,
                                                  const unsigned short* __restrict__ T4,
                                                  const int* __restrict__ fidx,
                                                  unsigned short* __restrict__ X) {
    __shared__ float red[KTOT];
    int col = blockIdx.x;
    int b = col >> 10;
    int c = threadIdx.x;
    int idx = fidx[col];
    float kx = (float)(idx % W);
    float ky = (float)(idx / W);

    const unsigned short* T; int h, w, s, base, segsize, cl, C;
    if (c < 64)       { T = T1; h = 240; w = 320; s = 2;  base = 0;   segsize = 64;  cl = c;       C = 64; }
    else if (c < 192) { T = T2; h = 120; w = 160; s = 4;  base = 64;  segsize = 128; cl = c - 64;  C = 128; }
    else if (c < 448) { T = T3; h = 60;  w = 80;  s = 8;  base = 192; segsize = 256; cl = c - 192; C = 256; }
    else              { T = T4; h = 30;  w = 40;  s = 16; base = 448; segsize = 256; cl = c - 448; C = 256; }

    float kxs = (kx - (float)s * 0.5f) + 0.5f;
    float kys = (ky - (float)s * 0.5f) + 0.5f;
    float gx = kxs / (float)(w * s - 1) * 2.0f - 1.0f;
    float gy = kys / (float)(h * s - 1) * 2.0f - 1.0f;
    float x = (gx + 1.0f) * 0.5f * (float)(w - 1);
    float y = (gy + 1.0f) * 0.5f * (float)(h - 1);
    float x0f = floorf(x), y0f = floorf(y);
    int x0 = (int)x0f, y0 = (int)y0f;
    float wx1 = x - x0f, wy1 = y - y0f;
    float wx0 = 1.0f - wx1, wy0 = 1.0f - wy1;
    auto tap = [&](int xi, int yi) -> float {
        bool v = (xi >= 0) && (xi < w) && (yi >= 0) && (yi < h);
        int xc = min(max(xi, 0), w - 1);
        int yc = min(max(yi, 0), h - 1);
        unsigned short u = T[((size_t)(b * h + yc) * w + xc) * C + cl];
        return v ? bf2f(u) : 0.0f;
    };
    float v = tap(x0, y0) * (wx0 * wy0) + tap(x0 + 1, y0) * (wx1 * wy0) +
              tap(x0, y0 + 1) * (wx0 * wy1) + tap(x0 + 1, y0 + 1) * (wx1 * wy1);

    red[c] = v * v;
    __syncthreads();
    #pragma unroll
    for (int off = 128; off > 0; off >>= 1) {
        if (off < segsize && cl < off) red[c] += red[c + off];
        __syncthreads();
    }
    float norm = sqrtf(red[base]);
    float denom = fmaxf(norm, 1e-12f);
    X[(size_t)col * KTOT + c] = (unsigned short)f2bf(v / denom);
}

// ===== fallback: direct CHW gather (used only if ws too small for transposes) =====
__global__ __launch_bounds__(704) void sample_chw(const float* __restrict__ d1,
                                                  const float* __restrict__ d2,
                                                  const float* __restrict__ cDa,
                                                  const float* __restrict__ d4,
                                                  const int* __restrict__ fidx,
                                                  unsigned short* __restrict__ X) {
    __shared__ float red[KTOT];
    int col = blockIdx.x;
    int b = col >> 10;
    int c = threadIdx.x;
    int idx = fidx[col];
    float kx = (float)(idx % W);
    float ky = (float)(idx / W);
    const float* map; int h, w, s, base, segsize, cl, C;
    if (c < 64)       { map = d1;  h = 240; w = 320; s = 2;  base = 0;   segsize = 64;  cl = c;       C = 64; }
    else if (c < 192) { map = d2;  h = 120; w = 160; s = 4;  base = 64;  segsize = 128; cl = c - 64;  C = 128; }
    else if (c < 448) { map = cDa; h = 60;  w = 80;  s = 8;  base = 192; segsize = 256; cl = c - 192; C = 256; }
    else              { map = d4;  h = 30;  w = 40;  s = 16; base = 448; segsize = 256; cl = c - 448; C = 256; }
    float kxs = (kx - (float)s * 0.5f) + 0.5f;
    float kys = (ky - (float)s * 0.5f) + 0.5f;
    float gx = kxs / (float)(w * s - 1) * 2.0f - 1.0f;
    float gy = kys / (float)(h * s - 1) * 2.0f - 1.0f;
    float x = (gx + 1.0f) * 0.5f * (float)(w - 1);
    float y = (gy + 1.0f) * 0.5f * (float)(h - 1);
    float x0f = floorf(x), y0f = floorf(y);
    int x0 = (int)x0f, y0 = (int)y0f;
    float wx1 = x - x0f, wy1 = y - y0f;
    float wx0 = 1.0f - wx1, wy0 = 1.0f - wy1;
    const float* plane = map + ((size_t)(b * C + cl)) * h * w;
    auto tap = [&](int xi, int yi) -> float {
        bool v = (xi >= 0) && (xi < w) && (yi >= 0) && (yi < h);
        int xc = min(max(xi, 0), w - 1);
        int yc = min(max(yi, 0), h - 1);
        return v ? plane[yc * w + xc] : 0.0f;
    };
    float v = tap(x0, y0) * (wx0 * wy0) + tap(x0 + 1, y0) * (wx1 * wy0) +
              tap(x0, y0 + 1) * (wx0 * wy1) + tap(x0 + 1, y0 + 1) * (wx1 * wy1);
    red[c] = v * v;
    __syncthreads();
    #pragma unroll
    for (int off = 128; off > 0; off >>= 1) {
        if (off < segsize && cl < off) red[c] += red[c + off];
        __syncthreads();
    }
    float norm = sqrtf(red[base]);
    float denom = fmaxf(norm, 1e-12f);
    X[(size_t)col * KTOT + c] = (unsigned short)f2bf(v / denom);
}

// ===== GEMM (bf16 MFMA): out[256,4096] = Mw[256,704] * X^T + bias; X bf16 =====
__global__ __launch_bounds__(256) void gemm_mfma(const float* __restrict__ Mw,
                                                 const unsigned short* __restrict__ X,
                                                 const float* __restrict__ biasf,
                                                 float* __restrict__ out) {
    __shared__ short As[64 * 68];
    __shared__ short Bs[64 * 68];
    int tid = threadIdx.x;
    int lane = tid & 63, w = tid >> 6;
    int r = lane & 15, quad = lane >> 4;
    int rowBase = blockIdx.y * 64, colBase = blockIdx.x * 64;
    int sm = tid >> 2, skq = (tid & 3) << 4;

    const float* pa = Mw + (size_t)(rowBase + sm) * KTOT + skq;
    const unsigned short* pb = X + (size_t)(colBase + sm) * KTOT + skq;
    float4 a0 = *(const float4*)(pa + 0), a1 = *(const float4*)(pa + 4);
    float4 a2 = *(const float4*)(pa + 8), a3 = *(const float4*)(pa + 12);
    s8v b01 = *(const s8v*)(pb);
    s8v b23 = *(const s8v*)(pb + 8);

    f4v acc[4];
    #pragma unroll
    for (int t = 0; t < 4; ++t) acc[t] = (f4v)0.0f;

    for (int kt = 0; kt < 11; ++kt) {
        __syncthreads();
        {
            s4v v0 = { f2bf(a0.x), f2bf(a0.y), f2bf(a0.z), f2bf(a0.w) };
            s4v v1 = { f2bf(a1.x), f2bf(a1.y), f2bf(a1.z), f2bf(a1.w) };
            s4v v2 = { f2bf(a2.x), f2bf(a2.y), f2bf(a2.z), f2bf(a2.w) };
            s4v v3 = { f2bf(a3.x), f2bf(a3.y), f2bf(a3.z), f2bf(a3.w) };
            *(s4v*)&As[sm * 68 + skq + 0]  = v0;
            *(s4v*)&As[sm * 68 + skq + 4]  = v1;
            *(s4v*)&As[sm * 68 + skq + 8]  = v2;
            *(s4v*)&As[sm * 68 + skq + 12] = v3;
            s4v u0 = { b01[0], b01[1], b01[2], b01[3] };
            s4v u1 = { b01[4], b01[5], b01[6], b01[7] };
            s4v u2 = { b23[0], b23[1], b23[2], b23[3] };
            s4v u3 = { b23[4], b23[5], b23[6], b23[7] };
            *(s4v*)&Bs[sm * 68 + skq + 0]  = u0;
            *(s4v*)&Bs[sm * 68 + skq + 4]  = u1;
            *(s4v*)&Bs[sm * 68 + skq + 8]  = u2;
            *(s4v*)&Bs[sm * 68 + skq + 12] = u3;
        }
        __syncthreads();
        if (kt < 10) {
            pa += 64; pb += 64;
            a0 = *(const float4*)(pa + 0); a1 = *(const float4*)(pa + 4);
            a2 = *(const float4*)(pa + 8); a3 = *(const float4*)(pa + 12);
            b01 = *(const s8v*)(pb);
            b23 = *(const s8v*)(pb + 8);
        }
        #pragma unroll
        for (int kk = 0; kk < 2; ++kk) {
            int aoff = (w * 16 + r) * 68 + kk * 32 + quad * 8;
            s4v alo = *(s4v*)&As[aoff];
            s4v ahi = *(s4v*)&As[aoff + 4];
            s8v af;
            af[0] = alo[0]; af[1] = alo[1]; af[2] = alo[2]; af[3] = alo[3];
            af[4] = ahi[0]; af[5] = ahi[1]; af[6] = ahi[2]; af[7] = ahi[3];
            #pragma unroll
            for (int t = 0; t < 4; ++t) {
                int boff = (t * 16 + r) * 68 + kk * 32 + quad * 8;
                s4v blo = *(s4v*)&Bs[boff];
                s4v bhi = *(s4v*)&Bs[boff + 4];
                s8v bf;
                bf[0] = blo[0]; bf[1] = blo[1]; bf[2] = blo[2]; bf[3] = blo[3];
                bf[4] = bhi[0]; bf[5] = bhi[1]; bf[6] = bhi[2]; bf[7] = bhi[3];
                acc[t] = __builtin_amdgcn_mfma_f32_16x16x32_bf16(af, bf, acc[t], 0, 0, 0);
            }
        }
    }
    #pragma unroll
    for (int t = 0; t < 4; ++t) {
        int colg = colBase + t * 16 + r;
        size_t obase = (size_t)(colg >> 10) * (256 * NKP) + (size_t)(colg & 1023);
        #pragma unroll
        for (int reg = 0; reg < 4; ++reg) {
            int row = rowBase + w * 16 + quad * 4 + reg;
            out[obase + (size_t)row * NKP] = acc[t][reg] + biasf[row];
        }
    }
}

// ================= launch =================
extern "C" void kernel_launch(void* const* d_in, const int* in_sizes, int n_in,
                              void* d_out, int out_size, void* d_ws, size_t ws_size,
                              hipStream_t stream) {
    const float* scores  = (const float*)d_in[0];
    const float* d1      = (const float*)d_in[1];
    const float* d2      = (const float*)d_in[2];
    const float* cDa     = (const float*)d_in[3];
    const float* d4      = (const float*)d_in[4];
    const float* lin0_w  = (const float*)d_in[5];
    const float* lin0_b  = (const float*)d_in[6];
    const float* lin1_w  = (const float*)d_in[7];
    const float* lin1_b  = (const float*)d_in[8];
    const float* lin2_w  = (const float*)d_in[9];
    const float* lin2_b  = (const float*)d_in[10];
    const float* merge_w = (const float*)d_in[11];
    const float* merge_b = (const float*)d_in[12];
    float* out = (float*)d_out;

    char* ws = (char*)d_ws;
    float* MASK = (float*)ws;                                        // 4,915,200 B
    unsigned short* Xb        = (unsigned short*)(ws + 4915200);     // 5,767,168 B
    unsigned long long* cand  = (unsigned long long*)(ws + 10682368);// 524,288 B
    int* cnt                  = (int*)(ws + 11206656);               // 1,024 B
    int* fidx                 = (int*)(ws + 11207680);               // 16,384 B
    float* Mw                 = (float*)(ws + 11224064);             // 720,896 B
    float* biasf              = (float*)(ws + 11944960);             // 1,024 B
    unsigned short* T1        = (unsigned short*)(ws + 11946240);    // 39,321,600 B
    unsigned short* T2        = (unsigned short*)(ws + 51267840);    // 19,660,800 B
    unsigned short* T3        = (unsigned short*)(ws + 70928640);    //  9,830,400 B
    unsigned short* T4        = (unsigned short*)(ws + 80759040);    //  2,457,600 B -> 83,216,640

    bool use_t = (ws_size >= 83216640ULL);
    dim3 tgrid(W / 32, H / 32, B);   // (20,15,4)

    fuse_all<<<705, 256, 0, stream>>>(merge_w, merge_b, lin0_w, lin0_b, lin1_w, lin1_b,
                                      lin2_w, lin2_b, Mw, biasf, cnt);
    nms1<<<tgrid, 256, 0, stream>>>(scores, MASK);
    nms2_compact<<<tgrid, 256, 0, stream>>>(scores, MASK, cand, cnt);
    topk<<<B, 1024, 0, stream>>>(cand, cnt, out, fidx);
    if (use_t) {
        transpose_hwc<64><<<dim3(5, 240, 4), 256, 0, stream>>>(d1, T1, 240, 320);
        transpose_hwc<128><<<dim3(3, 120, 8), 256, 0, stream>>>(d2, T2, 120, 160);
        transpose_hwc<256><<<dim3(2, 60, 16), 256, 0, stream>>>(cDa, T3, 60, 80);
        transpose_hwc<256><<<dim3(1, 30, 16), 256, 0, stream>>>(d4, T4, 30, 40);
        sample_hwc<<<B * NKP, KTOT, 0, stream>>>(T1, T2, T3, T4, fidx, Xb);
    } else {
        sample_chw<<<B * NKP, KTOT, 0, stream>>>(d1, d2, cDa, d4, fidx, Xb);
    }
    gemm_mfma<<<dim3(NCOL / 64, 256 / 64), 256, 0, stream>>>(Mw, Xb, biasf, out + B * NKP * 3);
}

// Round 6
// 424.651 us; speedup vs baseline: 1.0306x; 1.0306x over previous
//
#include <hip/hip_runtime.h>
#include <hip/hip_bf16.h>

#define B 4
#define H 480
#define W 640
#define HW (H*W)
#define BHW (B*H*W)
#define NKP 1024
#define THRESH 0.005f
#define CAP 16384
#define NCOL (B*NKP)
#define KTOT 704

typedef __attribute__((ext_vector_type(4))) short s4v;
typedef __attribute__((ext_vector_type(8))) short s8v;
typedef __attribute__((ext_vector_type(4))) float f4v;

__device__ __forceinline__ short f2bf(float f) {
    __hip_bfloat16 h = __float2bfloat16(f);
    return *(short*)&h;
}
__device__ __forceinline__ float bf2f(unsigned short u) {
    return __uint_as_float(((unsigned)u) << 16);
}

// ================= fused weights + bias + counter zero =================
__global__ void fuse_all(const float* __restrict__ merge_w, const float* __restrict__ merge_b,
                         const float* __restrict__ lin0_w, const float* __restrict__ lin0_b,
                         const float* __restrict__ lin1_w, const float* __restrict__ lin1_b,
                         const float* __restrict__ lin2_w, const float* __restrict__ lin2_b,
                         float* __restrict__ Mw, float* __restrict__ biasf, int* __restrict__ cnt) {
    if (blockIdx.x == 704) {
        int o = threadIdx.x;
        if (o < 4) cnt[o * 64] = 0;
        float acc = merge_b[o];
        for (int k = 0; k < 64; ++k)  acc += merge_w[o * KTOT + k] * lin2_b[k];
        for (int k = 0; k < 128; ++k) acc += merge_w[o * KTOT + 64 + k] * lin1_b[k];
        for (int k = 0; k < 256; ++k) acc += merge_w[o * KTOT + 448 + k] * lin0_b[k];
        biasf[o] = acc;
        return;
    }
    int e = blockIdx.x * 256 + threadIdx.x;
    int o = e / KTOT;
    int j = e - o * KTOT;
    float acc = 0.0f;
    if (j < 64) {
        for (int k = 0; k < 64; ++k) acc += merge_w[o * KTOT + k] * lin2_w[k * 64 + j];
    } else if (j < 192) {
        int jj = j - 64;
        for (int k = 0; k < 128; ++k) acc += merge_w[o * KTOT + 64 + k] * lin1_w[k * 128 + jj];
    } else if (j < 448) {
        acc = merge_w[o * KTOT + j];
    } else {
        int jj = j - 448;
        for (int k = 0; k < 256; ++k) acc += merge_w[o * KTOT + 448 + k] * lin0_w[k * 256 + jj];
    }
    Mw[o * KTOT + j] = acc;
}

// ================= NMS stage 1: mask0 = (S == pool9(S)), uchar out =================
__global__ __launch_bounds__(256) void nms1(const float* __restrict__ scores,
                                            unsigned char* __restrict__ mask) {
    __shared__ float tile[40][40];
    __shared__ float hm[40][32];
    int bz = blockIdx.z;
    int x0 = blockIdx.x * 32, y0 = blockIdx.y * 32;
    const float* sp = scores + bz * HW;
    for (int t = threadIdx.x; t < 1600; t += 256) {
        int ly = t / 40, lx = t - ly * 40;
        int gy = y0 - 4 + ly, gx = x0 - 4 + lx;
        tile[ly][lx] = (gy >= 0 && gy < H && gx >= 0 && gx < W) ? sp[gy * W + gx] : -INFINITY;
    }
    __syncthreads();
    for (int t = threadIdx.x; t < 1280; t += 256) {
        int ly = t >> 5, lx = t & 31;
        float m = tile[ly][lx];
        #pragma unroll
        for (int d = 1; d < 9; ++d) m = fmaxf(m, tile[ly][lx + d]);
        hm[ly][lx] = m;
    }
    __syncthreads();
    for (int t = threadIdx.x; t < 1024; t += 256) {
        int ly = t >> 5, lx = t & 31;
        float m = hm[ly][lx];
        #pragma unroll
        for (int d = 1; d < 9; ++d) m = fmaxf(m, hm[ly + d][lx]);
        float s = tile[ly + 4][lx + 4];
        mask[bz * HW + (y0 + ly) * W + x0 + lx] = (s == m) ? 1 : 0;
    }
}

// ===== one NMS recovery iteration: maskOut = maskIn | newmax(Z), Z = pool(maskIn)>0 ? -1 : S
// 32x32 out tile, halo 8. COMPACT variant also emits candidate keys.
template <bool COMPACT>
__global__ __launch_bounds__(256) void nms_iter(const float* __restrict__ scores,
                                                const unsigned char* __restrict__ maskIn,
                                                unsigned char* __restrict__ maskOut,
                                                unsigned long long* __restrict__ cand,
                                                int* __restrict__ cnt) {
    __shared__ int   Mi[48 * 48];   // mask in, local [0,48) = global -8
    __shared__ int   Ti[48 * 40];   // mask h-pass
    __shared__ float Sm[40 * 40];   // S, local [0,40) = global -4
    __shared__ float Zm[40 * 40];
    __shared__ float Tf[40 * 32];   // Z h-pass
    __shared__ int lcnt, gbase;
    int bz = blockIdx.z;
    int x0 = blockIdx.x * 32, y0 = blockIdx.y * 32;
    const float* sp = scores + bz * HW;
    const unsigned char* mp = maskIn + bz * HW;
    if (COMPACT && threadIdx.x == 0) lcnt = 0;
    for (int t = threadIdx.x; t < 2304; t += 256) {
        int ly = t / 48, lx = t - ly * 48;
        int gy = y0 - 8 + ly, gx = x0 - 8 + lx;
        Mi[t] = (gy >= 0 && gy < H && gx >= 0 && gx < W) ? (int)mp[gy * W + gx] : 0;
    }
    for (int t = threadIdx.x; t < 1600; t += 256) {
        int ly = t / 40, lx = t - ly * 40;
        int gy = y0 - 4 + ly, gx = x0 - 4 + lx;
        Sm[t] = (gy >= 0 && gy < H && gx >= 0 && gx < W) ? sp[gy * W + gx] : -1.0f;
    }
    __syncthreads();
    // mask pool h-pass: rows [0,48), cols [0,40)
    for (int t = threadIdx.x; t < 1920; t += 256) {
        int i = t / 40, c = t - i * 40;
        int m = Mi[i * 48 + c];
        #pragma unroll
        for (int d = 1; d < 9; ++d) m |= Mi[i * 48 + c + d];
        Ti[i * 40 + c] = m;
    }
    __syncthreads();
    // mask pool v-pass + Z = supp ? -1 : S  on [0,40)^2
    for (int t = threadIdx.x; t < 1600; t += 256) {
        int i = t / 40, c = t - i * 40;
        int m = Ti[i * 40 + c];
        #pragma unroll
        for (int d = 1; d < 9; ++d) m |= Ti[(i + d) * 40 + c];
        Zm[t] = m ? -1.0f : Sm[t];
    }
    __syncthreads();
    // Z pool h-pass: rows [0,40), cols [0,32)
    for (int t = threadIdx.x; t < 1280; t += 256) {
        int i = t >> 5, c = t & 31;
        float m = Zm[i * 40 + c];
        #pragma unroll
        for (int d = 1; d < 9; ++d) m = fmaxf(m, Zm[i * 40 + c + d]);
        Tf[i * 32 + c] = m;
    }
    __syncthreads();
    // v-pass + combine (+ optional compact), 4 px/thread
    unsigned long long keys[4];
    int nl = 0;
    #pragma unroll
    for (int q = 0; q < 4; ++q) {
        int t = threadIdx.x + q * 256;
        int r = t >> 5, c = t & 31;
        float m = Tf[r * 32 + c];
        #pragma unroll
        for (int d = 1; d < 9; ++d) m = fmaxf(m, Tf[(r + d) * 32 + c]);
        float Zc = Zm[(r + 4) * 40 + c + 4];
        bool nm = (Zc == m) && (Zc >= 0.0f);
        int m1 = Mi[(r + 8) * 48 + c + 8] | (nm ? 1 : 0);
        int gy = y0 + r, gx = x0 + c;
        if (!COMPACT) {
            maskOut[bz * HW + gy * W + gx] = (unsigned char)m1;
        } else {
            float sc = Sm[(r + 4) * 40 + c + 4];
            if (m1 && gy >= 4 && gy < H - 4 && gx >= 4 && gx < W - 4 && sc > THRESH) {
                unsigned rr = (unsigned)(gy * W + gx);
                unsigned bits = __float_as_uint(sc) | 0x80000000u;
                keys[nl++] = ((unsigned long long)bits << 32) |
                             (unsigned long long)(0xFFFFFFFFu - rr);
            }
        }
    }
    if (COMPACT) {
        int lpos = 0;
        if (nl) lpos = atomicAdd(&lcnt, nl);
        __syncthreads();
        if (threadIdx.x == 0) gbase = (lcnt > 0) ? atomicAdd(&cnt[bz * 64], lcnt) : 0;
        __syncthreads();
        for (int j = 0; j < nl; ++j) {
            int p = gbase + lpos + j;
            if (p < CAP) cand[(size_t)bz * CAP + p] = keys[j];
        }
    }
}

// ===== topk: two-level histogram select + rank-based ordering (no bitonic) =====
__global__ __launch_bounds__(1024) void topk(const unsigned long long* __restrict__ cand,
                                             const int* __restrict__ cnt,
                                             float* __restrict__ out, int* __restrict__ fidx) {
    __shared__ int hist[2048];
    __shared__ unsigned long long buf[4096];
    __shared__ int scnt, spiv1, spiv2, sabove;
    int b = blockIdx.x, tid = threadIdx.x;
    int m = cnt[b * 64]; if (m > CAP) m = CAP;
    const unsigned long long* cb = cand + (size_t)b * CAP;
    int target = (m < 1024) ? m : 1024;

    hist[tid] = 0; hist[tid + 1024] = 0;
    if (tid == 0) { scnt = 0; spiv1 = 2048; spiv2 = 0; sabove = 0; }
    __syncthreads();
    // pass 1: histogram bits [63:53], wave-aggregated (dense score band shares bins)
    for (int i = tid; i < m; i += 1024) {
        int bin = (int)(cb[i] >> 53) & 0x7FF;
        int first = __builtin_amdgcn_readfirstlane(bin);
        unsigned long long same = __ballot(bin == first);
        if (same == ~0ULL) {
            if ((tid & 63) == 0) atomicAdd(&hist[first], 64);
        } else {
            atomicAdd(&hist[bin], 1);
        }
    }
    __syncthreads();
    for (int d = 1; d < 2048; d <<= 1) {
        int v0 = hist[tid] + ((tid + d < 2048) ? hist[tid + d] : 0);
        int v1 = hist[tid + 1024] + ((tid + 1024 + d < 2048) ? hist[tid + 1024 + d] : 0);
        __syncthreads();
        hist[tid] = v0; hist[tid + 1024] = v1;
        __syncthreads();
    }
    if (target > 0) {
        for (int t = tid; t < 2048; t += 1024) {
            int c = hist[t];
            int cn = (t < 2047) ? hist[t + 1] : 0;
            if (c >= target && cn < target) { spiv1 = t; sabove = cn; }
        }
    }
    __syncthreads();
    int piv1 = spiv1;
    int target2 = target - sabove;
    hist[tid] = 0; hist[tid + 1024] = 0;
    __syncthreads();
    // pass 2: histogram bits [52:42] within pivot bin
    for (int i = tid; i < m; i += 1024) {
        unsigned long long k = cb[i];
        if (((int)(k >> 53) & 0x7FF) == piv1)
            atomicAdd(&hist[(int)(k >> 42) & 0x7FF], 1);
    }
    __syncthreads();
    for (int d = 1; d < 2048; d <<= 1) {
        int v0 = hist[tid] + ((tid + d < 2048) ? hist[tid + d] : 0);
        int v1 = hist[tid + 1024] + ((tid + 1024 + d < 2048) ? hist[tid + 1024 + d] : 0);
        __syncthreads();
        hist[tid] = v0; hist[tid + 1024] = v1;
        __syncthreads();
    }
    if (target > 0) {
        for (int t = tid; t < 2048; t += 1024) {
            int c = hist[t];
            int cn = (t < 2047) ? hist[t + 1] : 0;
            if (c >= target2 && cn < target2) spiv2 = t;
        }
    }
    __syncthreads();
    int piv2 = spiv2;
    for (int i = tid; i < m; i += 1024) {
        unsigned long long k = cb[i];
        int b1 = (int)(k >> 53) & 0x7FF;
        bool sel = (target > 0) &&
                   (b1 > piv1 || (b1 == piv1 && (((int)(k >> 42) & 0x7FF) >= piv2)));
        if (sel) {
            int p = atomicAdd(&scnt, 1);
            if (p < 4096) buf[p] = k;
        }
    }
    __syncthreads();
    int sc_ = scnt; if (sc_ > 4096) sc_ = 4096;
    // defaults for tail slots
    if (tid >= target) {
        int bn = b * NKP + tid;
        out[bn * 2 + 0] = 0.0f;
        out[bn * 2 + 1] = 0.0f;
        out[B * NKP * 2 + bn] = -1.0f;
        fidx[bn] = 0;
    }
    // rank-sort: rank = #{keys greater}; keys unique -> unique ranks
    unsigned long long k1 = (tid < sc_) ? buf[tid] : 0ULL;
    unsigned long long k2 = (tid + 1024 < sc_) ? buf[tid + 1024] : 0ULL;
    int r1 = 0, r2 = 0;
    for (int j = 0; j < sc_; ++j) {
        unsigned long long v = buf[j];
        r1 += (v > k1) ? 1 : 0;
        r2 += (v > k2) ? 1 : 0;
    }
    #pragma unroll
    for (int q = 0; q < 2; ++q) {
        int i = tid + q * 1024;
        unsigned long long k = q ? k2 : k1;
        int r = q ? r2 : r1;
        if (i < sc_ && r < target) {
            unsigned ord = (unsigned)(k >> 32);
            float sc = __uint_as_float(ord ^ 0x80000000u);
            unsigned idx = 0xFFFFFFFFu - (unsigned)(k & 0xFFFFFFFFu);
            int bn = b * NKP + r;
            out[bn * 2 + 0] = (float)(idx % W);
            out[bn * 2 + 1] = (float)(idx / W);
            out[B * NKP * 2 + bn] = sc;
            fidx[bn] = (int)idx;
        }
    }
}

// ===== CHW fp32 -> HWC bf16 transpose (d1, d2 only) =====
template <int CMAP>
__global__ __launch_bounds__(256) void transpose_hwc(const float* __restrict__ in,
                                                     unsigned short* __restrict__ out,
                                                     int h, int w) {
    __shared__ float Ts[64][65];
    int lx = threadIdx.x & 63, lr = threadIdx.x >> 6;
    int x0 = blockIdx.x * 64;
    int y = blockIdx.y;
    int bz = blockIdx.z;
    int b = bz / (CMAP / 64);
    int c0 = (bz % (CMAP / 64)) * 64;
    int x = x0 + lx;
    #pragma unroll
    for (int i = 0; i < 16; ++i) {
        int cl = lr + i * 4;
        float v = 0.0f;
        if (x < w) v = in[(((size_t)(b * CMAP + c0 + cl)) * h + y) * w + x];
        Ts[cl][lx] = v;
    }
    __syncthreads();
    #pragma unroll
    for (int j = 0; j < 16; ++j) {
        int xl = lr + j * 4;
        int xg = x0 + xl;
        if (xg < w)
            out[((size_t)(b * h + y) * w + xg) * CMAP + c0 + lx] =
                (unsigned short)f2bf(Ts[lx][xl]);
    }
}

// ===== descriptor gather: d1/d2 from HWC bf16, cDa/d4 from CHW fp32 (L2-resident) =====
__global__ __launch_bounds__(704) void sample_mix(const unsigned short* __restrict__ T1,
                                                  const unsigned short* __restrict__ T2,
                                                  const float* __restrict__ cDa,
                                                  const float* __restrict__ d4,
                                                  const int* __restrict__ fidx,
                                                  unsigned short* __restrict__ X) {
    __shared__ float red[KTOT];
    int col = blockIdx.x;
    int b = col >> 10;
    int c = threadIdx.x;
    int idx = fidx[col];
    float kx = (float)(idx % W);
    float ky = (float)(idx / W);

    int h, w, s, base, segsize, cl;
    if (c < 64)       { h = 240; w = 320; s = 2;  base = 0;   segsize = 64;  cl = c; }
    else if (c < 192) { h = 120; w = 160; s = 4;  base = 64;  segsize = 128; cl = c - 64; }
    else if (c < 448) { h = 60;  w = 80;  s = 8;  base = 192; segsize = 256; cl = c - 192; }
    else              { h = 30;  w = 40;  s = 16; base = 448; segsize = 256; cl = c - 448; }

    float kxs = (kx - (float)s * 0.5f) + 0.5f;
    float kys = (ky - (float)s * 0.5f) + 0.5f;
    float gx = kxs / (float)(w * s - 1) * 2.0f - 1.0f;
    float gy = kys / (float)(h * s - 1) * 2.0f - 1.0f;
    float x = (gx + 1.0f) * 0.5f * (float)(w - 1);
    float y = (gy + 1.0f) * 0.5f * (float)(h - 1);
    float x0f = floorf(x), y0f = floorf(y);
    int x0 = (int)x0f, y0 = (int)y0f;
    float wx1 = x - x0f, wy1 = y - y0f;
    float wx0 = 1.0f - wx1, wy0 = 1.0f - wy1;

    float v;
    if (c < 192) {
        const unsigned short* T = (c < 64) ? T1 : T2;
        int C2 = (c < 64) ? 64 : 128;
        auto tap = [&](int xi, int yi) -> float {
            bool vv = (xi >= 0) && (xi < w) && (yi >= 0) && (yi < h);
            int xc = min(max(xi, 0), w - 1);
            int yc = min(max(yi, 0), h - 1);
            unsigned short u = T[((size_t)(b * h + yc) * w + xc) * C2 + cl];
            return vv ? bf2f(u) : 0.0f;
        };
        v = tap(x0, y0) * (wx0 * wy0) + tap(x0 + 1, y0) * (wx1 * wy0) +
            tap(x0, y0 + 1) * (wx0 * wy1) + tap(x0 + 1, y0 + 1) * (wx1 * wy1);
    } else {
        const float* plane = (c < 448) ? (cDa + ((size_t)(b * 256 + cl)) * 4800)
                                       : (d4 + ((size_t)(b * 256 + cl)) * 1200);
        auto tap = [&](int xi, int yi) -> float {
            bool vv = (xi >= 0) && (xi < w) && (yi >= 0) && (yi < h);
            int xc = min(max(xi, 0), w - 1);
            int yc = min(max(yi, 0), h - 1);
            return vv ? plane[yc * w + xc] : 0.0f;
        };
        v = tap(x0, y0) * (wx0 * wy0) + tap(x0 + 1, y0) * (wx1 * wy0) +
            tap(x0, y0 + 1) * (wx0 * wy1) + tap(x0 + 1, y0 + 1) * (wx1 * wy1);
    }

    red[c] = v * v;
    __syncthreads();
    #pragma unroll
    for (int off = 128; off > 0; off >>= 1) {
        if (off < segsize && cl < off) red[c] += red[c + off];
        __syncthreads();
    }
    float norm = sqrtf(red[base]);
    float denom = fmaxf(norm, 1e-12f);
    X[(size_t)col * KTOT + c] = (unsigned short)f2bf(v / denom);
}

// ===== GEMM (bf16 MFMA): out[256,4096] = Mw[256,704] * X^T + bias; X bf16 =====
__global__ __launch_bounds__(256) void gemm_mfma(const float* __restrict__ Mw,
                                                 const unsigned short* __restrict__ X,
                                                 const float* __restrict__ biasf,
                                                 float* __restrict__ out) {
    __shared__ short As[64 * 68];
    __shared__ short Bs[64 * 68];
    int tid = threadIdx.x;
    int lane = tid & 63, w = tid >> 6;
    int r = lane & 15, quad = lane >> 4;
    int rowBase = blockIdx.y * 64, colBase = blockIdx.x * 64;
    int sm = tid >> 2, skq = (tid & 3) << 4;

    const float* pa = Mw + (size_t)(rowBase + sm) * KTOT + skq;
    const unsigned short* pb = X + (size_t)(colBase + sm) * KTOT + skq;
    float4 a0 = *(const float4*)(pa + 0), a1 = *(const float4*)(pa + 4);
    float4 a2 = *(const float4*)(pa + 8), a3 = *(const float4*)(pa + 12);
    s8v b01 = *(const s8v*)(pb);
    s8v b23 = *(const s8v*)(pb + 8);

    f4v acc[4];
    #pragma unroll
    for (int t = 0; t < 4; ++t) acc[t] = (f4v)0.0f;

    for (int kt = 0; kt < 11; ++kt) {
        __syncthreads();
        {
            s4v v0 = { f2bf(a0.x), f2bf(a0.y), f2bf(a0.z), f2bf(a0.w) };
            s4v v1 = { f2bf(a1.x), f2bf(a1.y), f2bf(a1.z), f2bf(a1.w) };
            s4v v2 = { f2bf(a2.x), f2bf(a2.y), f2bf(a2.z), f2bf(a2.w) };
            s4v v3 = { f2bf(a3.x), f2bf(a3.y), f2bf(a3.z), f2bf(a3.w) };
            *(s4v*)&As[sm * 68 + skq + 0]  = v0;
            *(s4v*)&As[sm * 68 + skq + 4]  = v1;
            *(s4v*)&As[sm * 68 + skq + 8]  = v2;
            *(s4v*)&As[sm * 68 + skq + 12] = v3;
            s4v u0 = { b01[0], b01[1], b01[2], b01[3] };
            s4v u1 = { b01[4], b01[5], b01[6], b01[7] };
            s4v u2 = { b23[0], b23[1], b23[2], b23[3] };
            s4v u3 = { b23[4], b23[5], b23[6], b23[7] };
            *(s4v*)&Bs[sm * 68 + skq + 0]  = u0;
            *(s4v*)&Bs[sm * 68 + skq + 4]  = u1;
            *(s4v*)&Bs[sm * 68 + skq + 8]  = u2;
            *(s4v*)&Bs[sm * 68 + skq + 12] = u3;
        }
        __syncthreads();
        if (kt < 10) {
            pa += 64; pb += 64;
            a0 = *(const float4*)(pa + 0); a1 = *(const float4*)(pa + 4);
            a2 = *(const float4*)(pa + 8); a3 = *(const float4*)(pa + 12);
            b01 = *(const s8v*)(pb);
            b23 = *(const s8v*)(pb + 8);
        }
        #pragma unroll
        for (int kk = 0; kk < 2; ++kk) {
            int aoff = (w * 16 + r) * 68 + kk * 32 + quad * 8;
            s4v alo = *(s4v*)&As[aoff];
            s4v ahi = *(s4v*)&As[aoff + 4];
            s8v af;
            af[0] = alo[0]; af[1] = alo[1]; af[2] = alo[2]; af[3] = alo[3];
            af[4] = ahi[0]; af[5] = ahi[1]; af[6] = ahi[2]; af[7] = ahi[3];
            #pragma unroll
            for (int t = 0; t < 4; ++t) {
                int boff = (t * 16 + r) * 68 + kk * 32 + quad * 8;
                s4v blo = *(s4v*)&Bs[boff];
                s4v bhi = *(s4v*)&Bs[boff + 4];
                s8v bf;
                bf[0] = blo[0]; bf[1] = blo[1]; bf[2] = blo[2]; bf[3] = blo[3];
                bf[4] = bhi[0]; bf[5] = bhi[1]; bf[6] = bhi[2]; bf[7] = bhi[7 - 7 + 4 - 4 + 4]; // bf[4]
                bf[4] = bhi[0]; bf[5] = bhi[1]; bf[6] = bhi[2]; bf[7] = bhi[3];
                acc[t] = __builtin_amdgcn_mfma_f32_16x16x32_bf16(af, bf, acc[t], 0, 0, 0);
            }
        }
    }
    #pragma unroll
    for (int t = 0; t < 4; ++t) {
        int colg = colBase + t * 16 + r;
        size_t obase = (size_t)(colg >> 10) * (256 * NKP) + (size_t)(colg & 1023);
        #pragma unroll
        for (int reg = 0; reg < 4; ++reg) {
            int row = rowBase + w * 16 + quad * 4 + reg;
            out[obase + (size_t)row * NKP] = acc[t][reg] + biasf[row];
        }
    }
}

// ================= launch =================
extern "C" void kernel_launch(void* const* d_in, const int* in_sizes, int n_in,
                              void* d_out, int out_size, void* d_ws, size_t ws_size,
                              hipStream_t stream) {
    const float* scores  = (const float*)d_in[0];
    const float* d1      = (const float*)d_in[1];
    const float* d2      = (const float*)d_in[2];
    const float* cDa     = (const float*)d_in[3];
    const float* d4      = (const float*)d_in[4];
    const float* lin0_w  = (const float*)d_in[5];
    const float* lin0_b  = (const float*)d_in[6];
    const float* lin1_w  = (const float*)d_in[7];
    const float* lin1_b  = (const float*)d_in[8];
    const float* lin2_w  = (const float*)d_in[9];
    const float* lin2_b  = (const float*)d_in[10];
    const float* merge_w = (const float*)d_in[11];
    const float* merge_b = (const float*)d_in[12];
    float* out = (float*)d_out;

    char* ws = (char*)d_ws;
    unsigned char* M0         = (unsigned char*)ws;                  // 1,228,800
    unsigned char* M1         = (unsigned char*)(ws + 1228800);      // 1,228,800
    unsigned short* Xb        = (unsigned short*)(ws + 2457600);     // 5,767,168
    unsigned long long* cand  = (unsigned long long*)(ws + 8224768); // 524,288
    int* cnt                  = (int*)(ws + 8749056);                // 1,024
    int* fidx                 = (int*)(ws + 8750080);                // 16,384
    float* Mw                 = (float*)(ws + 8766464);              // 720,896
    float* biasf              = (float*)(ws + 9487360);              // 1,024
    unsigned short* T1        = (unsigned short*)(ws + 9488384);     // 39,321,600
    unsigned short* T2        = (unsigned short*)(ws + 48809984);    // 19,660,800 -> 68,470,784

    dim3 tgrid(W / 32, H / 32, B);   // (20,15,4)

    fuse_all<<<705, 256, 0, stream>>>(merge_w, merge_b, lin0_w, lin0_b, lin1_w, lin1_b,
                                      lin2_w, lin2_b, Mw, biasf, cnt);
    nms1<<<tgrid, 256, 0, stream>>>(scores, M0);
    nms_iter<false><<<tgrid, 256, 0, stream>>>(scores, M0, M1, nullptr, nullptr);
    nms_iter<true><<<tgrid, 256, 0, stream>>>(scores, M1, nullptr, cand, cnt);
    topk<<<B, 1024, 0, stream>>>(cand, cnt, out, fidx);
    transpose_hwc<64><<<dim3(5, 240, 4), 256, 0, stream>>>(d1, T1, 240, 320);
    transpose_hwc<128><<<dim3(3, 120, 8), 256, 0, stream>>>(d2, T2, 120, 160);
    sample_mix<<<B * NKP, KTOT, 0, stream>>>(T1, T2, cDa, d4, fidx, Xb);
    gemm_mfma<<<dim3(NCOL / 64, 256 / 64), 256, 0, stream>>>(Mw, Xb, biasf, out + B * NKP * 3);
}